// Round 9
// baseline (5261.905 us; speedup 1.0000x reference)
//
#include <hip/hip_runtime.h>
#include <cmath>

#define BATCH  2
#define SEQ    2048
#define DMODEL 1024
#define NHEAD  16
#define HDIM   64
#define KTOP   8
#define KKEEP  10   // top-8 + slack for bitwise ties at the threshold

// KC=512 CONFIRMED bit-exact vs harness numpy reference (round 6/8 pass).
#define KC_PANEL 512

// ---------------------------------------------------------------------------
// Projection GEMM replicating OpenBLAS sgemm fp32 rounding (KC=512 panels).
// MODE 0: out in head layout [b][h][s][d]; MODE 1: flat [row][col].
// ---------------------------------------------------------------------------
template<int MODE>
__global__ __launch_bounds__(256)
void proj_gemm(const float* __restrict__ A, const float* __restrict__ W,
               const float* __restrict__ bias, float* __restrict__ outp)
{
    __shared__ float As[32][68];   // [k][m]
    __shared__ float Bs[32][68];   // [k][n]
    const int tid  = threadIdx.x;
    const int tx   = tid & 15, ty = tid >> 4;
    const int row0 = blockIdx.x * 64;
    const int col0 = blockIdx.y * 64;
    const int lm   = tid >> 2;          // 0..63
    const int lk   = (tid & 3) * 8;     // 0,8,16,24

    float acc[4][4] = {};   // open panel chain
    float sum[4][4] = {};   // closed panels

    for (int kb = 0; kb < DMODEL; kb += 32) {
        if (kb && (kb % KC_PANEL == 0)) {
            #pragma unroll
            for (int i = 0; i < 4; ++i)
                #pragma unroll
                for (int j = 0; j < 4; ++j) { sum[i][j] += acc[i][j]; acc[i][j] = 0.f; }
        }
        __syncthreads();
        const float* srcA = A + (size_t)(row0 + lm) * DMODEL + kb + lk;
        float4 a0 = *(const float4*)srcA;
        float4 a1 = *(const float4*)(srcA + 4);
        const float* srcB = W + (size_t)(col0 + lm) * DMODEL + kb + lk;
        float4 b0 = *(const float4*)srcB;
        float4 b1 = *(const float4*)(srcB + 4);
        As[lk+0][lm]=a0.x; As[lk+1][lm]=a0.y; As[lk+2][lm]=a0.z; As[lk+3][lm]=a0.w;
        As[lk+4][lm]=a1.x; As[lk+5][lm]=a1.y; As[lk+6][lm]=a1.z; As[lk+7][lm]=a1.w;
        Bs[lk+0][lm]=b0.x; Bs[lk+1][lm]=b0.y; Bs[lk+2][lm]=b0.z; Bs[lk+3][lm]=b0.w;
        Bs[lk+4][lm]=b1.x; Bs[lk+5][lm]=b1.y; Bs[lk+6][lm]=b1.z; Bs[lk+7][lm]=b1.w;
        __syncthreads();
        #pragma unroll
        for (int kk = 0; kk < 32; ++kk) {   // ascending k, fused-FMA chain
            float4 af = *(const float4*)&As[kk][ty*4];
            float4 bf = *(const float4*)&Bs[kk][tx*4];
            float a_[4] = {af.x, af.y, af.z, af.w};
            float b_[4] = {bf.x, bf.y, bf.z, bf.w};
            #pragma unroll
            for (int i = 0; i < 4; ++i)
                #pragma unroll
                for (int j = 0; j < 4; ++j)
                    acc[i][j] = fmaf(a_[i], b_[j], acc[i][j]);
        }
    }

    #pragma unroll
    for (int i = 0; i < 4; ++i) {
        const int row = row0 + ty*4 + i;
        const int bb  = row >> 11;
        const int ss  = row & (SEQ - 1);
        #pragma unroll
        for (int j = 0; j < 4; ++j) {
            const int col = col0 + tx*4 + j;
            float r = sum[i][j] + acc[i][j];   // close final panel
            r = r + bias[col];                 // bias == 0.0f: exact
            if constexpr (MODE == 1) {
                outp[(size_t)row * DMODEL + col] = r;
            } else {
                const int h = col >> 6, d = col & 63;
                outp[(((size_t)(bb*NHEAD + h))*SEQ + ss)*HDIM + d] = r;
            }
        }
    }
}

// ---------------------------------------------------------------------------
// Exact streaming top-KKEEP merge (wave-cooperative, replicated state).
// No readfirstlane (round-7 bug: float->i32 implicit conversion truncates);
// the __shfl_xor butterfly already replicates the winner to all 64 lanes.
// ---------------------------------------------------------------------------
__device__ __forceinline__ void topk_merge(float cand, int cidx,
                                           float (&tv)[KKEEP], int (&ti)[KKEEP])
{
    while (__ballot(cand > tv[KKEEP-1])) {
        float mv = cand; int mi = cidx;
        #pragma unroll
        for (int off = 32; off > 0; off >>= 1) {
            float ov = __shfl_xor(mv, off);
            int   oi = __shfl_xor(mi, off);
            if (ov > mv || (ov == mv && oi < mi)) { mv = ov; mi = oi; }
        }
        float v = mv; int ix = mi;
        #pragma unroll
        for (int s = 0; s < KKEEP; ++s) {
            const bool gt = v > tv[s];
            const float otv = tv[s]; const int oti = ti[s];
            tv[s] = gt ? v  : otv;  ti[s] = gt ? ix  : oti;
            v     = gt ? otv : v;   ix    = gt ? oti : ix;
        }
        if (cidx == mi) cand = -INFINITY;
    }
}

// softmax over kept set (>= thr, ties included) + sparse PV (fp32, smooth).
__device__ __forceinline__ void finish_row(const float (&tv)[KKEEP], const int (&ti)[KKEEP],
                                           const float* __restrict__ V,
                                           float* __restrict__ AO,
                                           int bh, int row, int lane)
{
    const float thr = tv[KTOP-1];
    const float m   = tv[0];
    float wv[KKEEP]; float wsum = 0.f;
    #pragma unroll
    for (int s = 0; s < KKEEP; ++s) {
        const bool kept = (tv[s] >= thr);      // slots 0..7 always; 8,9 iff tied
        wv[s] = kept ? expf(tv[s] - m) : 0.f;
        wsum += wv[s];
    }
    float o = 0.f;
    #pragma unroll
    for (int s = 0; s < KKEEP; ++s)
        o = fmaf(wv[s] / wsum, V[(size_t)ti[s]*HDIM + lane], o);
    AO[((size_t)(bh >> 4) * SEQ + row) * DMODEL + (bh & 15) * HDIM + lane] = o;
}

// ---------------------------------------------------------------------------
// Attention: per (b,h), 8 query rows/block, 4 waves x 2 rows (q in VGPRs).
// 256-thread block + __launch_bounds__(256,1) -> 1 wave/SIMD floor -> VGPR
// budget up to 512: the ~225 live regs (qa/qb 128 + kv 16 + topk 40 + staging)
// fit WITHOUT scratch spills (round 8: 512-thread block capped VGPR at 128,
// spilled q arrays -> WRITE_SIZE 181 MB, no speedup).
// K chunk (64 keys x 64 dims) in LDS, layout [j][d], XOR swizzle: float4-chunk
// t stored at t ^ (j&15) -> conflict-free ds_read_b128/ds_write_b128.
// Double-buffered: global->reg issued before compute, reg->LDS after.
// Dot = numpy einsum npyv cascade (mul+add, no FMA, contract(off)) -- values
// bit-identical to round 6/8's passing kernels.
// ---------------------------------------------------------------------------
__global__ __launch_bounds__(256, 1)
void attn_topk(const float* __restrict__ Qh, const float* __restrict__ Kh,
               const float* __restrict__ Vh, float* __restrict__ AO)
{
    __shared__ float Ks[2][64*64];      // 32 KB, swizzled [j][d]
    __shared__ float Qs[8][64];         //  2 KB
    const int tid  = threadIdx.x;
    const int lane = tid & 63;
    const int w    = tid >> 6;          // 0..3
    const int bh   = blockIdx.y;        // 0..31
    const int row0 = blockIdx.x * 8;
    const size_t hbase = (size_t)bh * SEQ * HDIM;
    const float* Q = Qh + hbase;
    const float* K = Kh + hbase;
    const float* V = Vh + hbase;

    // ---- stage 8 Q rows (512 floats, 2 per thread) ----
    {
        float2 q2 = *(const float2*)(Q + (size_t)row0 * HDIM + tid * 2);
        ((float2*)&Qs[0][0])[tid] = q2;
    }

    // ---- K staging: thread -> (key sj, 4 float4-chunks sf..sf+3) ----
    const int sj = tid >> 2;            // 0..63 key within chunk
    const int sf = (tid & 3) * 4;       // first float4-chunk: 0,4,8,12
    int wofs[4];
    #pragma unroll
    for (int f = 0; f < 4; ++f)
        wofs[f] = sj*64 + 4*((sf + f) ^ (sj & 15));

    float4 sreg[4];
    {   // preload chunk 0 (coalesced: 64B contiguous per thread)
        const float* src = K + (size_t)sj * HDIM + sf * 4;
        #pragma unroll
        for (int f = 0; f < 4; ++f) sreg[f] = *(const float4*)(src + 4*f);
    }
    #pragma unroll
    for (int f = 0; f < 4; ++f) *(float4*)&Ks[0][wofs[f]] = sreg[f];
    __syncthreads();

    // ---- hoist this wave's 2 q-rows into VGPRs (uniform broadcast reads) ----
    const int r0 = w*2, r1 = w*2 + 1;
    float qa[64], qb[64];
    #pragma unroll
    for (int d4 = 0; d4 < 64; d4 += 4) {
        float4 a = *(const float4*)&Qs[r0][d4];
        float4 b = *(const float4*)&Qs[r1][d4];
        qa[d4+0]=a.x; qa[d4+1]=a.y; qa[d4+2]=a.z; qa[d4+3]=a.w;
        qb[d4+0]=b.x; qb[d4+1]=b.y; qb[d4+2]=b.z; qb[d4+3]=b.w;
    }

    float tv0[KKEEP], tv1[KKEEP]; int ti0[KKEEP], ti1[KKEEP];
    #pragma unroll
    for (int s = 0; s < KKEEP; ++s) {
        tv0[s] = -INFINITY; tv1[s] = -INFINITY; ti0[s] = 0; ti1[s] = 0;
    }

    for (int c = 0; c < SEQ/64; ++c) {
        // issue next chunk's global loads early (latency hidden under compute)
        if (c + 1 < SEQ/64) {
            const float* src = K + (size_t)((c+1)*64 + sj) * HDIM + sf * 4;
            #pragma unroll
            for (int f = 0; f < 4; ++f) sreg[f] = *(const float4*)(src + 4*f);
        }

        const float* kb = &Ks[c & 1][0];
        float raw0, raw1;
        {
            #pragma clang fp contract(off)
            float A0=0.f,A1=0.f,A2=0.f,A3=0.f;
            float B0=0.f,B1=0.f,B2=0.f,B3=0.f;
            #pragma unroll
            for (int t = 0; t < 4; ++t) {   // 16-dim blocks, ascending
                float kv[16];
                #pragma unroll
                for (int f = 0; f < 4; ++f) {
                    const int tc = 4*t + f;
                    float4 k4 = *(const float4*)&kb[lane*64 + 4*(tc ^ (lane & 15))];
                    kv[f*4+0]=k4.x; kv[f*4+1]=k4.y; kv[f*4+2]=k4.z; kv[f*4+3]=k4.w;
                }
                const int u = t*16;
                A0 = qa[u+0]*kv[0] + (qa[u+4]*kv[4] + (qa[u+8]*kv[8]   + (qa[u+12]*kv[12] + A0)));
                A1 = qa[u+1]*kv[1] + (qa[u+5]*kv[5] + (qa[u+9]*kv[9]   + (qa[u+13]*kv[13] + A1)));
                A2 = qa[u+2]*kv[2] + (qa[u+6]*kv[6] + (qa[u+10]*kv[10] + (qa[u+14]*kv[14] + A2)));
                A3 = qa[u+3]*kv[3] + (qa[u+7]*kv[7] + (qa[u+11]*kv[11] + (qa[u+15]*kv[15] + A3)));
                B0 = qb[u+0]*kv[0] + (qb[u+4]*kv[4] + (qb[u+8]*kv[8]   + (qb[u+12]*kv[12] + B0)));
                B1 = qb[u+1]*kv[1] + (qb[u+5]*kv[5] + (qb[u+9]*kv[9]   + (qb[u+13]*kv[13] + B1)));
                B2 = qb[u+2]*kv[2] + (qb[u+6]*kv[6] + (qb[u+10]*kv[10] + (qb[u+14]*kv[14] + B2)));
                B3 = qb[u+3]*kv[3] + (qb[u+7]*kv[7] + (qb[u+11]*kv[11] + (qb[u+15]*kv[15] + B3)));
            }
            raw0 = (A0 + A1) + (A2 + A3);
            raw1 = (B0 + B1) + (B2 + B3);
        }
        const int cidx = c*64 + lane;
        topk_merge(raw0 * 0.125f, cidx, tv0, ti0);   // /sqrt(64) exact
        topk_merge(raw1 * 0.125f, cidx, tv1, ti1);

        // write staged regs for chunk c+1 (other buffer; no read/write overlap)
        if (c + 1 < SEQ/64) {
            #pragma unroll
            for (int f = 0; f < 4; ++f) *(float4*)&Ks[(c+1) & 1][wofs[f]] = sreg[f];
        }
        __syncthreads();
    }

    finish_row(tv0, ti0, V, AO, bh, row0 + r0, lane);
    finish_row(tv1, ti1, V, AO, bh, row0 + r1, lane);
}

// ---------------------------------------------------------------------------
extern "C" void kernel_launch(void* const* d_in, const int* in_sizes, int n_in,
                              void* d_out, int out_size, void* d_ws, size_t ws_size,
                              hipStream_t stream)
{
    const float* q  = (const float*)d_in[0];
    const float* k  = (const float*)d_in[1];
    const float* v  = (const float*)d_in[2];
    const float* Wq = (const float*)d_in[3];
    const float* bq = (const float*)d_in[4];
    const float* Wk = (const float*)d_in[5];
    const float* bk = (const float*)d_in[6];
    const float* Wv = (const float*)d_in[7];
    const float* bv = (const float*)d_in[8];
    const float* Wo = (const float*)d_in[9];
    const float* bo = (const float*)d_in[10];
    float* out = (float*)d_out;

    const size_t nH = (size_t)BATCH * NHEAD * SEQ * HDIM;  // 4,194,304
    float* Qh = (float*)d_ws;          // 16.78 MB
    float* Kh = Qh + nH;               // 16.78 MB
    float* Vh = Kh + nH;               // 16.78 MB
    float* AO = Vh + nH;               // 16.78 MB  (total ~67 MB)

    dim3 gg(64, 16), gb(256);
    hipLaunchKernelGGL((proj_gemm<0>), gg, gb, 0, stream, q, Wq, bq, Qh);
    hipLaunchKernelGGL((proj_gemm<0>), gg, gb, 0, stream, k, Wk, bk, Kh);
    hipLaunchKernelGGL((proj_gemm<0>), gg, gb, 0, stream, v, Wv, bv, Vh);
    hipLaunchKernelGGL(attn_topk, dim3(SEQ/8, BATCH*NHEAD), dim3(256), 0, stream,
                       Qh, Kh, Vh, AO);
    hipLaunchKernelGGL((proj_gemm<1>), gg, gb, 0, stream, AO, Wo, bo, out);
}

// Round 10
// 4800.639 us; speedup vs baseline: 1.0961x; 1.0961x over previous
//
#include <hip/hip_runtime.h>
#include <cmath>

#define BATCH  2
#define SEQ    2048
#define DMODEL 1024
#define NHEAD  16
#define HDIM   64
#define KTOP   8
#define KKEEP  10   // top-8 + slack for bitwise ties at the threshold

// KC=512 CONFIRMED bit-exact vs harness numpy reference (rounds 6/8/9 pass).
#define KC_PANEL 512

// ---------------------------------------------------------------------------
// Projection GEMM replicating OpenBLAS sgemm fp32 rounding (KC=512 panels).
// MODE 0: out in head layout [b][h][s][d]; MODE 1: flat [row][col].
// ---------------------------------------------------------------------------
template<int MODE>
__global__ __launch_bounds__(256)
void proj_gemm(const float* __restrict__ A, const float* __restrict__ W,
               const float* __restrict__ bias, float* __restrict__ outp)
{
    __shared__ float As[32][68];   // [k][m]
    __shared__ float Bs[32][68];   // [k][n]
    const int tid  = threadIdx.x;
    const int tx   = tid & 15, ty = tid >> 4;
    const int row0 = blockIdx.x * 64;
    const int col0 = blockIdx.y * 64;
    const int lm   = tid >> 2;          // 0..63
    const int lk   = (tid & 3) * 8;     // 0,8,16,24

    float acc[4][4] = {};   // open panel chain
    float sum[4][4] = {};   // closed panels

    for (int kb = 0; kb < DMODEL; kb += 32) {
        if (kb && (kb % KC_PANEL == 0)) {
            #pragma unroll
            for (int i = 0; i < 4; ++i)
                #pragma unroll
                for (int j = 0; j < 4; ++j) { sum[i][j] += acc[i][j]; acc[i][j] = 0.f; }
        }
        __syncthreads();
        const float* srcA = A + (size_t)(row0 + lm) * DMODEL + kb + lk;
        float4 a0 = *(const float4*)srcA;
        float4 a1 = *(const float4*)(srcA + 4);
        const float* srcB = W + (size_t)(col0 + lm) * DMODEL + kb + lk;
        float4 b0 = *(const float4*)srcB;
        float4 b1 = *(const float4*)(srcB + 4);
        As[lk+0][lm]=a0.x; As[lk+1][lm]=a0.y; As[lk+2][lm]=a0.z; As[lk+3][lm]=a0.w;
        As[lk+4][lm]=a1.x; As[lk+5][lm]=a1.y; As[lk+6][lm]=a1.z; As[lk+7][lm]=a1.w;
        Bs[lk+0][lm]=b0.x; Bs[lk+1][lm]=b0.y; Bs[lk+2][lm]=b0.z; Bs[lk+3][lm]=b0.w;
        Bs[lk+4][lm]=b1.x; Bs[lk+5][lm]=b1.y; Bs[lk+6][lm]=b1.z; Bs[lk+7][lm]=b1.w;
        __syncthreads();
        #pragma unroll
        for (int kk = 0; kk < 32; ++kk) {   // ascending k, fused-FMA chain
            float4 af = *(const float4*)&As[kk][ty*4];
            float4 bf = *(const float4*)&Bs[kk][tx*4];
            float a_[4] = {af.x, af.y, af.z, af.w};
            float b_[4] = {bf.x, bf.y, bf.z, bf.w};
            #pragma unroll
            for (int i = 0; i < 4; ++i)
                #pragma unroll
                for (int j = 0; j < 4; ++j)
                    acc[i][j] = fmaf(a_[i], b_[j], acc[i][j]);
        }
    }

    #pragma unroll
    for (int i = 0; i < 4; ++i) {
        const int row = row0 + ty*4 + i;
        const int bb  = row >> 11;
        const int ss  = row & (SEQ - 1);
        #pragma unroll
        for (int j = 0; j < 4; ++j) {
            const int col = col0 + tx*4 + j;
            float r = sum[i][j] + acc[i][j];   // close final panel
            r = r + bias[col];                 // bias == 0.0f: exact
            if constexpr (MODE == 1) {
                outp[(size_t)row * DMODEL + col] = r;
            } else {
                const int h = col >> 6, d = col & 63;
                outp[(((size_t)(bb*NHEAD + h))*SEQ + ss)*HDIM + d] = r;
            }
        }
    }
}

// ---------------------------------------------------------------------------
// Lane-LOCAL sorted top-KKEEP insert: pure per-lane VALU, no shuffles/ballots
// in the hot loop (rounds 6-9's wave-streaming merge spent ~36 ds_bpermute
// ops per chunk per wave -- that was the hidden LDS-pipe load).
// ---------------------------------------------------------------------------
__device__ __forceinline__ void lane_insert(float cand, int cidx,
                                            float (&tv)[KKEEP], int (&ti)[KKEEP])
{
    if (cand > tv[KKEEP-1]) {
        float v = cand; int ix = cidx;
        #pragma unroll
        for (int s = 0; s < KKEEP; ++s) {
            const bool gt = v > tv[s];
            const float otv = tv[s]; const int oti = ti[s];
            tv[s] = gt ? v  : otv;  ti[s] = gt ? ix  : oti;
            v     = gt ? otv : v;   ix    = gt ? oti : ix;
        }
    }
}

// Exact wave merge of 64 lane-local sorted lists -> replicated global top-10.
// KKEEP pop-max rounds; key indices are globally unique so exactly one lane
// pops per round. Runs ONCE per row (not per chunk). Static indexing only.
__device__ __forceinline__ void wave_merge(float (&tvL)[KKEEP], int (&tiL)[KKEEP],
                                           float (&tv)[KKEEP],  int (&ti)[KKEEP])
{
    #pragma unroll
    for (int s = 0; s < KKEEP; ++s) {
        float mv = tvL[0]; int mi = tiL[0];
        #pragma unroll
        for (int off = 32; off > 0; off >>= 1) {
            float ov = __shfl_xor(mv, off);
            int   oi = __shfl_xor(mi, off);
            if (ov > mv || (ov == mv && oi < mi)) { mv = ov; mi = oi; }
        }
        tv[s] = mv; ti[s] = mi;
        if (tvL[0] == mv && tiL[0] == mi) {   // unique winner pops its head
            #pragma unroll
            for (int p = 0; p < KKEEP-1; ++p) { tvL[p] = tvL[p+1]; tiL[p] = tiL[p+1]; }
            tvL[KKEEP-1] = -INFINITY; tiL[KKEEP-1] = -1;
        }
    }
}

// softmax over kept set (>= thr, ties included) + sparse PV (fp32, smooth).
__device__ __forceinline__ void finish_row(const float (&tv)[KKEEP], const int (&ti)[KKEEP],
                                           const float* __restrict__ V,
                                           float* __restrict__ AO,
                                           int bh, int row, int lane)
{
    const float thr = tv[KTOP-1];
    const float m   = tv[0];
    float wv[KKEEP]; float wsum = 0.f;
    #pragma unroll
    for (int s = 0; s < KKEEP; ++s) {
        const bool kept = (tv[s] >= thr);      // slots 0..7 always; 8,9 iff tied
        wv[s] = kept ? expf(tv[s] - m) : 0.f;
        wsum += wv[s];
    }
    float o = 0.f;
    #pragma unroll
    for (int s = 0; s < KKEEP; ++s)
        o = fmaf(wv[s] / wsum, V[(size_t)ti[s]*HDIM + lane], o);
    AO[((size_t)(bh >> 4) * SEQ + row) * DMODEL + (bh & 15) * HDIM + lane] = o;
}

// ---------------------------------------------------------------------------
// Attention: per (b,h), 16 query rows/block, 8 waves x 2 rows, q in VGPRs.
// __launch_bounds__(512, 2): 8-wave block needs 2 waves/SIMD -> VGPR cap 256;
// ~220 live (qa/qb 128 + topk 40 + kv 16 + staging/misc) -> no spills
// (R8's cap-128 spill caused 181 MB scratch; R9's 4-wave block lost latency
// hiding). Lane j scores keys c*64+j -> lane-local top-k, merge once at end.
// K chunk in LDS, [key][dim] XOR-swizzled (float4-chunk t at t^(key&15)):
// conflict-free b128 reads/writes. Double-buffered, 1 barrier/chunk.
// Dot = numpy einsum npyv cascade (mul+add, no FMA, contract(off)) -- values
// bit-identical to rounds 6/8/9's passing kernels.
// ---------------------------------------------------------------------------
__global__ __launch_bounds__(512, 2)
void attn_topk(const float* __restrict__ Qh, const float* __restrict__ Kh,
               const float* __restrict__ Vh, float* __restrict__ AO)
{
    __shared__ float Ks[2][64*64];      // 32 KB, swizzled [j][d]
    __shared__ float Qs[16][64];        //  4 KB
    const int tid  = threadIdx.x;
    const int lane = tid & 63;
    const int w    = tid >> 6;          // 0..7
    const int bh   = blockIdx.y;        // 0..31
    const int row0 = blockIdx.x * 16;
    const size_t hbase = (size_t)bh * SEQ * HDIM;
    const float* Q = Qh + hbase;
    const float* K = Kh + hbase;
    const float* V = Vh + hbase;

    // ---- stage 16 Q rows (1024 floats, 2 per thread) ----
    {
        float2 q2 = *(const float2*)(Q + (size_t)row0 * HDIM + tid * 2);
        ((float2*)&Qs[0][0])[tid] = q2;
    }

    // ---- K staging: thread -> (key sj, 2 float4-chunks sf, sf+1) ----
    const int sj = tid >> 3;            // 0..63 key within chunk
    const int sf = (tid & 7) * 2;       // float4-chunk: 0,2,...,14
    const int wofs0 = sj*64 + 4*((sf    ) ^ (sj & 15));
    const int wofs1 = sj*64 + 4*((sf + 1) ^ (sj & 15));

    float4 sreg0, sreg1;
    {   // preload chunk 0 (32B contiguous per thread, coalesced)
        const float* src = K + (size_t)sj * HDIM + sf * 4;
        sreg0 = *(const float4*)src;
        sreg1 = *(const float4*)(src + 4);
    }
    *(float4*)&Ks[0][wofs0] = sreg0;
    *(float4*)&Ks[0][wofs1] = sreg1;
    __syncthreads();

    // ---- hoist this wave's 2 q-rows into VGPRs ----
    const int r0 = w*2, r1 = w*2 + 1;
    float qa[64], qb[64];
    #pragma unroll
    for (int d4 = 0; d4 < 64; d4 += 4) {
        float4 a = *(const float4*)&Qs[r0][d4];
        float4 b = *(const float4*)&Qs[r1][d4];
        qa[d4+0]=a.x; qa[d4+1]=a.y; qa[d4+2]=a.z; qa[d4+3]=a.w;
        qb[d4+0]=b.x; qb[d4+1]=b.y; qb[d4+2]=b.z; qb[d4+3]=b.w;
    }

    float tv0[KKEEP], tv1[KKEEP]; int ti0[KKEEP], ti1[KKEEP];
    #pragma unroll
    for (int s = 0; s < KKEEP; ++s) {
        tv0[s] = -INFINITY; tv1[s] = -INFINITY; ti0[s] = -1; ti1[s] = -1;
    }

    for (int c = 0; c < SEQ/64; ++c) {
        // issue next chunk's global loads early (hidden under compute)
        if (c + 1 < SEQ/64) {
            const float* src = K + (size_t)((c+1)*64 + sj) * HDIM + sf * 4;
            sreg0 = *(const float4*)src;
            sreg1 = *(const float4*)(src + 4);
        }

        const float* kb = &Ks[c & 1][0];
        float raw0, raw1;
        {
            #pragma clang fp contract(off)
            float A0=0.f,A1=0.f,A2=0.f,A3=0.f;
            float B0=0.f,B1=0.f,B2=0.f,B3=0.f;
            #pragma unroll
            for (int t = 0; t < 4; ++t) {   // 16-dim blocks, ascending
                float kv[16];
                #pragma unroll
                for (int f = 0; f < 4; ++f) {
                    const int tc = 4*t + f;
                    float4 k4 = *(const float4*)&kb[lane*64 + 4*(tc ^ (lane & 15))];
                    kv[f*4+0]=k4.x; kv[f*4+1]=k4.y; kv[f*4+2]=k4.z; kv[f*4+3]=k4.w;
                }
                const int u = t*16;
                A0 = qa[u+0]*kv[0] + (qa[u+4]*kv[4] + (qa[u+8]*kv[8]   + (qa[u+12]*kv[12] + A0)));
                A1 = qa[u+1]*kv[1] + (qa[u+5]*kv[5] + (qa[u+9]*kv[9]   + (qa[u+13]*kv[13] + A1)));
                A2 = qa[u+2]*kv[2] + (qa[u+6]*kv[6] + (qa[u+10]*kv[10] + (qa[u+14]*kv[14] + A2)));
                A3 = qa[u+3]*kv[3] + (qa[u+7]*kv[7] + (qa[u+11]*kv[11] + (qa[u+15]*kv[15] + A3)));
                B0 = qb[u+0]*kv[0] + (qb[u+4]*kv[4] + (qb[u+8]*kv[8]   + (qb[u+12]*kv[12] + B0)));
                B1 = qb[u+1]*kv[1] + (qb[u+5]*kv[5] + (qb[u+9]*kv[9]   + (qb[u+13]*kv[13] + B1)));
                B2 = qb[u+2]*kv[2] + (qb[u+6]*kv[6] + (qb[u+10]*kv[10] + (qb[u+14]*kv[14] + B2)));
                B3 = qb[u+3]*kv[3] + (qb[u+7]*kv[7] + (qb[u+11]*kv[11] + (qb[u+15]*kv[15] + B3)));
            }
            raw0 = (A0 + A1) + (A2 + A3);
            raw1 = (B0 + B1) + (B2 + B3);
        }
        const int cidx = c*64 + lane;
        lane_insert(raw0 * 0.125f, cidx, tv0, ti0);   // /sqrt(64) exact
        lane_insert(raw1 * 0.125f, cidx, tv1, ti1);

        // write staged regs for chunk c+1 (other buffer; barrier-separated)
        if (c + 1 < SEQ/64) {
            *(float4*)&Ks[(c+1) & 1][wofs0] = sreg0;
            *(float4*)&Ks[(c+1) & 1][wofs1] = sreg1;
        }
        __syncthreads();
    }

    // ---- one exact wave merge per row, then finish ----
    float gv[KKEEP]; int gi[KKEEP];
    wave_merge(tv0, ti0, gv, gi);
    finish_row(gv, gi, V, AO, bh, row0 + r0, lane);
    wave_merge(tv1, ti1, gv, gi);
    finish_row(gv, gi, V, AO, bh, row0 + r1, lane);
}

// ---------------------------------------------------------------------------
extern "C" void kernel_launch(void* const* d_in, const int* in_sizes, int n_in,
                              void* d_out, int out_size, void* d_ws, size_t ws_size,
                              hipStream_t stream)
{
    const float* q  = (const float*)d_in[0];
    const float* k  = (const float*)d_in[1];
    const float* v  = (const float*)d_in[2];
    const float* Wq = (const float*)d_in[3];
    const float* bq = (const float*)d_in[4];
    const float* Wk = (const float*)d_in[5];
    const float* bk = (const float*)d_in[6];
    const float* Wv = (const float*)d_in[7];
    const float* bv = (const float*)d_in[8];
    const float* Wo = (const float*)d_in[9];
    const float* bo = (const float*)d_in[10];
    float* out = (float*)d_out;

    const size_t nH = (size_t)BATCH * NHEAD * SEQ * HDIM;  // 4,194,304
    float* Qh = (float*)d_ws;          // 16.78 MB
    float* Kh = Qh + nH;               // 16.78 MB
    float* Vh = Kh + nH;               // 16.78 MB
    float* AO = Vh + nH;               // 16.78 MB  (total ~67 MB)

    dim3 gg(64, 16), gb(256);
    hipLaunchKernelGGL((proj_gemm<0>), gg, gb, 0, stream, q, Wq, bq, Qh);
    hipLaunchKernelGGL((proj_gemm<0>), gg, gb, 0, stream, k, Wk, bk, Kh);
    hipLaunchKernelGGL((proj_gemm<0>), gg, gb, 0, stream, v, Wv, bv, Vh);
    hipLaunchKernelGGL(attn_topk, dim3(SEQ/16, BATCH*NHEAD), dim3(512), 0, stream,
                       Qh, Kh, Vh, AO);
    hipLaunchKernelGGL((proj_gemm<1>), gg, gb, 0, stream, AO, Wo, bo, out);
}

// Round 11
// 1458.659 us; speedup vs baseline: 3.6074x; 3.2911x over previous
//
#include <hip/hip_runtime.h>
#include <cmath>

#define BATCH  2
#define SEQ    2048
#define DMODEL 1024
#define NHEAD  16
#define HDIM   64
#define KTOP   8
#define KKEEP  10   // top-8 + slack for bitwise ties at the threshold

// KC=512 CONFIRMED bit-exact vs harness numpy reference (rounds 6/8/9/10 pass).
#define KC_PANEL 512

// ---------------------------------------------------------------------------
// Projection GEMM replicating OpenBLAS sgemm fp32 rounding (KC=512 panels).
// MODE 0: out in head layout [b][h][s][d]; MODE 1: flat [row][col].
// ---------------------------------------------------------------------------
template<int MODE>
__global__ __launch_bounds__(256)
void proj_gemm(const float* __restrict__ A, const float* __restrict__ W,
               const float* __restrict__ bias, float* __restrict__ outp)
{
    __shared__ float As[32][68];   // [k][m]
    __shared__ float Bs[32][68];   // [k][n]
    const int tid  = threadIdx.x;
    const int tx   = tid & 15, ty = tid >> 4;
    const int row0 = blockIdx.x * 64;
    const int col0 = blockIdx.y * 64;
    const int lm   = tid >> 2;          // 0..63
    const int lk   = (tid & 3) * 8;     // 0,8,16,24

    float acc[4][4] = {};   // open panel chain
    float sum[4][4] = {};   // closed panels

    for (int kb = 0; kb < DMODEL; kb += 32) {
        if (kb && (kb % KC_PANEL == 0)) {
            #pragma unroll
            for (int i = 0; i < 4; ++i)
                #pragma unroll
                for (int j = 0; j < 4; ++j) { sum[i][j] += acc[i][j]; acc[i][j] = 0.f; }
        }
        __syncthreads();
        const float* srcA = A + (size_t)(row0 + lm) * DMODEL + kb + lk;
        float4 a0 = *(const float4*)srcA;
        float4 a1 = *(const float4*)(srcA + 4);
        const float* srcB = W + (size_t)(col0 + lm) * DMODEL + kb + lk;
        float4 b0 = *(const float4*)srcB;
        float4 b1 = *(const float4*)(srcB + 4);
        As[lk+0][lm]=a0.x; As[lk+1][lm]=a0.y; As[lk+2][lm]=a0.z; As[lk+3][lm]=a0.w;
        As[lk+4][lm]=a1.x; As[lk+5][lm]=a1.y; As[lk+6][lm]=a1.z; As[lk+7][lm]=a1.w;
        Bs[lk+0][lm]=b0.x; Bs[lk+1][lm]=b0.y; Bs[lk+2][lm]=b0.z; Bs[lk+3][lm]=b0.w;
        Bs[lk+4][lm]=b1.x; Bs[lk+5][lm]=b1.y; Bs[lk+6][lm]=b1.z; Bs[lk+7][lm]=b1.w;
        __syncthreads();
        #pragma unroll
        for (int kk = 0; kk < 32; ++kk) {   // ascending k, fused-FMA chain
            float4 af = *(const float4*)&As[kk][ty*4];
            float4 bf = *(const float4*)&Bs[kk][tx*4];
            float a_[4] = {af.x, af.y, af.z, af.w};
            float b_[4] = {bf.x, bf.y, bf.z, bf.w};
            #pragma unroll
            for (int i = 0; i < 4; ++i)
                #pragma unroll
                for (int j = 0; j < 4; ++j)
                    acc[i][j] = fmaf(a_[i], b_[j], acc[i][j]);
        }
    }

    #pragma unroll
    for (int i = 0; i < 4; ++i) {
        const int row = row0 + ty*4 + i;
        const int bb  = row >> 11;
        const int ss  = row & (SEQ - 1);
        #pragma unroll
        for (int j = 0; j < 4; ++j) {
            const int col = col0 + tx*4 + j;
            float r = sum[i][j] + acc[i][j];   // close final panel
            r = r + bias[col];                 // bias == 0.0f: exact
            if constexpr (MODE == 1) {
                outp[(size_t)row * DMODEL + col] = r;
            } else {
                const int h = col >> 6, d = col & 63;
                outp[(((size_t)(bb*NHEAD + h))*SEQ + ss)*HDIM + d] = r;
            }
        }
    }
}

// ---------------------------------------------------------------------------
// Attention, lane = query row. 256 threads = 4 waves = 256 rows per block.
// - q row: 64 VGPRs per lane (its own registers; no LDS, no SGPR, no spill --
//   R8/R10 showed 512-thread blocks cap VGPR at 128 and spill q to scratch).
// - K chunk (64 keys x 64 dims, 16 KB) staged in LDS [key][dim], double-
//   buffered. All 64 lanes read the SAME key's float4 -> uniform-address
//   broadcast ds_read_b128: no bank conflicts, ~issue-cost only.
// - top-k: fully lane-local sorted insert (ZERO shuffles/ballots in hot loop;
//   R6-R10's per-chunk wave merges were the hidden LDS-pipe load, 1.68e7
//   bank-conflict counts). Keys arrive in ascending index order; '>' insert
//   keeps earliest index on ties == jax/np top_k tie semantics (R6-verified).
// - finish: per-lane softmax over kept set (>= tv[7], ties incl.) + sparse
//   PV gather + row write. No cross-lane ops anywhere.
// Dot = numpy einsum npyv cascade (mul+add, no FMA, contract(off)), bit-
// identical values to rounds 6/8/9/10's passing kernels.
// ---------------------------------------------------------------------------
__global__ __launch_bounds__(256, 2)
void attn_topk(const float* __restrict__ Qh, const float* __restrict__ Kh,
               const float* __restrict__ Vh, float* __restrict__ AO)
{
    __shared__ float Ks[2][64*64];      // 2 x 16 KB, [key][dim]
    const int tid  = threadIdx.x;
    const int lane = tid & 63;
    const int w    = tid >> 6;          // 0..3
    const int bh   = blockIdx.y;        // 0..31
    const int srow = blockIdx.x * 256 + w * 64 + lane;   // this lane's row
    const size_t hbase = (size_t)bh * SEQ * HDIM;
    const float* Q = Qh + hbase;
    const float* K = Kh + hbase;
    const float* V = Vh + hbase;

    // ---- this lane's q row -> VGPRs (one-time, 16 float4) ----
    float q[64];
    {
        const float* qsrc = Q + (size_t)srow * HDIM;
        #pragma unroll
        for (int d4 = 0; d4 < 16; ++d4) {
            float4 t4 = *(const float4*)(qsrc + d4*4);
            q[d4*4+0]=t4.x; q[d4*4+1]=t4.y; q[d4*4+2]=t4.z; q[d4*4+3]=t4.w;
        }
    }

    // ---- K staging map: thread -> (key tid>>2, 16 floats at (tid&3)*16) ----
    const int skey = tid >> 2;          // 0..63
    const int sflt = (tid & 3) * 16;    // 0,16,32,48

    float4 sreg[4];
    {   // preload chunk 0 (64 B contiguous per thread, coalesced)
        const float* src = K + (size_t)skey * HDIM + sflt;
        #pragma unroll
        for (int f = 0; f < 4; ++f) sreg[f] = *(const float4*)(src + 4*f);
    }
    #pragma unroll
    for (int f = 0; f < 4; ++f)
        *(float4*)&Ks[0][skey*64 + sflt + 4*f] = sreg[f];
    __syncthreads();

    // ---- lane-local top-KKEEP state (sorted descending) ----
    float tv[KKEEP]; int ti[KKEEP];
    #pragma unroll
    for (int s = 0; s < KKEEP; ++s) { tv[s] = -INFINITY; ti[s] = -1; }

    for (int c = 0; c < SEQ/64; ++c) {
        // issue next chunk's global loads early (hidden under 64-key compute)
        if (c + 1 < SEQ/64) {
            const float* src = K + (size_t)((c+1)*64 + skey) * HDIM + sflt;
            #pragma unroll
            for (int f = 0; f < 4; ++f) sreg[f] = *(const float4*)(src + 4*f);
        }
        const float* kb = &Ks[c & 1][0];

        #pragma unroll 2
        for (int j = 0; j < 64; ++j) {
            float raw;
            {
                #pragma clang fp contract(off)
                float A0=0.f, A1=0.f, A2=0.f, A3=0.f;
                #pragma unroll
                for (int t = 0; t < 4; ++t) {   // 16-dim blocks, ascending
                    float kv[16];
                    #pragma unroll
                    for (int f = 0; f < 4; ++f) {
                        float4 k4 = *(const float4*)&kb[j*64 + t*16 + 4*f];  // broadcast
                        kv[f*4+0]=k4.x; kv[f*4+1]=k4.y; kv[f*4+2]=k4.z; kv[f*4+3]=k4.w;
                    }
                    const int u = t*16;
                    A0 = q[u+0]*kv[0] + (q[u+4]*kv[4] + (q[u+8]*kv[8]   + (q[u+12]*kv[12] + A0)));
                    A1 = q[u+1]*kv[1] + (q[u+5]*kv[5] + (q[u+9]*kv[9]   + (q[u+13]*kv[13] + A1)));
                    A2 = q[u+2]*kv[2] + (q[u+6]*kv[6] + (q[u+10]*kv[10] + (q[u+14]*kv[14] + A2)));
                    A3 = q[u+3]*kv[3] + (q[u+7]*kv[7] + (q[u+11]*kv[11] + (q[u+15]*kv[15] + A3)));
                }
                raw = (A0 + A1) + (A2 + A3);
            }
            const float cand = raw * 0.125f;     // /sqrt(64) exact
            if (cand > tv[KKEEP-1]) {            // lane-local sorted insert
                float v = cand; int ix = c*64 + j;
                #pragma unroll
                for (int s = 0; s < KKEEP; ++s) {
                    const bool gt = v > tv[s];
                    const float otv = tv[s]; const int oti = ti[s];
                    tv[s] = gt ? v  : otv;  ti[s] = gt ? ix  : oti;
                    v     = gt ? otv : v;   ix    = gt ? oti : ix;
                }
            }
        }

        // write staged regs for chunk c+1 (other buffer; last read of that
        // buffer completed before the previous barrier)
        if (c + 1 < SEQ/64) {
            #pragma unroll
            for (int f = 0; f < 4; ++f)
                *(float4*)&Ks[(c+1) & 1][skey*64 + sflt + 4*f] = sreg[f];
        }
        __syncthreads();
    }

    // ---- per-lane finish: softmax over kept set + sparse PV ----
    const float thr = tv[KTOP-1];
    const float m   = tv[0];
    float wv[KKEEP]; float wsum = 0.f;
    #pragma unroll
    for (int s = 0; s < KKEEP; ++s) {
        wv[s] = (tv[s] >= thr) ? expf(tv[s] - m) : 0.f;   // slots 8,9 iff tied
        wsum += wv[s];
    }

    float o[64];
    #pragma unroll
    for (int d = 0; d < 64; ++d) o[d] = 0.f;
    #pragma unroll
    for (int s = 0; s < KKEEP; ++s) {
        if (__ballot(wv[s] != 0.f)) {            // wave-uniform skip (s=8,9)
            const float wgt = wv[s] / wsum;      // 0 for non-kept lanes: exact
            const float* vrow = V + (size_t)ti[s] * HDIM;
            #pragma unroll
            for (int d4 = 0; d4 < 16; ++d4) {
                float4 vv = *(const float4*)(vrow + d4*4);
                o[d4*4+0] = fmaf(wgt, vv.x, o[d4*4+0]);
                o[d4*4+1] = fmaf(wgt, vv.y, o[d4*4+1]);
                o[d4*4+2] = fmaf(wgt, vv.z, o[d4*4+2]);
                o[d4*4+3] = fmaf(wgt, vv.w, o[d4*4+3]);
            }
        }
    }

    // AO flat layout [b][s][h*64+d]
    float* dst = AO + ((size_t)(bh >> 4) * SEQ + srow) * DMODEL + (bh & 15) * HDIM;
    #pragma unroll
    for (int d4 = 0; d4 < 16; ++d4) {
        float4 ov; ov.x = o[d4*4+0]; ov.y = o[d4*4+1]; ov.z = o[d4*4+2]; ov.w = o[d4*4+3];
        *(float4*)(dst + d4*4) = ov;
    }
}

// ---------------------------------------------------------------------------
extern "C" void kernel_launch(void* const* d_in, const int* in_sizes, int n_in,
                              void* d_out, int out_size, void* d_ws, size_t ws_size,
                              hipStream_t stream)
{
    const float* q  = (const float*)d_in[0];
    const float* k  = (const float*)d_in[1];
    const float* v  = (const float*)d_in[2];
    const float* Wq = (const float*)d_in[3];
    const float* bq = (const float*)d_in[4];
    const float* Wk = (const float*)d_in[5];
    const float* bk = (const float*)d_in[6];
    const float* Wv = (const float*)d_in[7];
    const float* bv = (const float*)d_in[8];
    const float* Wo = (const float*)d_in[9];
    const float* bo = (const float*)d_in[10];
    float* out = (float*)d_out;

    const size_t nH = (size_t)BATCH * NHEAD * SEQ * HDIM;  // 4,194,304
    float* Qh = (float*)d_ws;          // 16.78 MB
    float* Kh = Qh + nH;               // 16.78 MB
    float* Vh = Kh + nH;               // 16.78 MB
    float* AO = Vh + nH;               // 16.78 MB  (total ~67 MB)

    dim3 gg(64, 16), gb(256);
    hipLaunchKernelGGL((proj_gemm<0>), gg, gb, 0, stream, q, Wq, bq, Qh);
    hipLaunchKernelGGL((proj_gemm<0>), gg, gb, 0, stream, k, Wk, bk, Kh);
    hipLaunchKernelGGL((proj_gemm<0>), gg, gb, 0, stream, v, Wv, bv, Vh);
    hipLaunchKernelGGL(attn_topk, dim3(SEQ/256, BATCH*NHEAD), dim3(256), 0, stream,
                       Qh, Kh, Vh, AO);
    hipLaunchKernelGGL((proj_gemm<1>), gg, gb, 0, stream, AO, Wo, bo, out);
}